// Round 9
// baseline (66.024 us; speedup 1.0000x reference)
//
#include <hip/hip_runtime.h>

#define NUM_INPUT   256
#define NUM_OUTPUT  64
#define MAX_DEPTH   10
#define N_INTERNAL  1023
#define STAGED_NODES 31          // tree levels 0..4 staged in LDS (31 KB)
#define STAGED_DEPTH 5
#define ELEMS_PER_WAVE 4         // 16 lanes per element
#define WAVES_PER_BLOCK 8
#define THREADS (WAVES_PER_BLOCK * 64)          // 512
#define ELEMS_PER_BLOCK (WAVES_PER_BLOCK * ELEMS_PER_WAVE)  // 32

// Sum-reduce across each 16-lane row using DPP row_ror (VALU pipe, no DS ops).
__device__ __forceinline__ float group16_reduce_add(float acc) {
    int t;
    t = __builtin_amdgcn_update_dpp(0, __float_as_int(acc), 0x121, 0xf, 0xf, true); // row_ror:1
    acc += __int_as_float(t);
    t = __builtin_amdgcn_update_dpp(0, __float_as_int(acc), 0x122, 0xf, 0xf, true); // row_ror:2
    acc += __int_as_float(t);
    t = __builtin_amdgcn_update_dpp(0, __float_as_int(acc), 0x124, 0xf, 0xf, true); // row_ror:4
    acc += __int_as_float(t);
    t = __builtin_amdgcn_update_dpp(0, __float_as_int(acc), 0x128, 0xf, 0xf, true); // row_ror:8
    acc += __int_as_float(t);
    return acc;
}

// Product-reduce across each 16-lane row (same rotation pattern, multiply).
__device__ __forceinline__ float group16_reduce_mul(float v) {
    int t;
    t = __builtin_amdgcn_update_dpp(0, __float_as_int(v), 0x121, 0xf, 0xf, true);
    v *= __int_as_float(t);
    t = __builtin_amdgcn_update_dpp(0, __float_as_int(v), 0x122, 0xf, 0xf, true);
    v *= __int_as_float(t);
    t = __builtin_amdgcn_update_dpp(0, __float_as_int(v), 0x124, 0xf, 0xf, true);
    v *= __int_as_float(t);
    t = __builtin_amdgcn_update_dpp(0, __float_as_int(v), 0x128, 0xf, 0xf, true);
    v *= __int_as_float(t);
    return v;
}

// Branchless per-component select (compiles to v_cndmask).
__device__ __forceinline__ float4 sel4(bool c, float4 r, float4 l) {
    float4 o;
    o.x = c ? r.x : l.x;
    o.y = c ? r.y : l.y;
    o.z = c ? r.z : l.z;
    o.w = c ? r.w : l.w;
    return o;
}

__global__ __launch_bounds__(THREADS, 4) void ogtree_kernel(
    const float* __restrict__ x,
    const float* __restrict__ W,
    const float* __restrict__ b,
    const float* __restrict__ alpha,
    const float* __restrict__ leaves,
    float* __restrict__ out)
{
    __shared__ float lds_w[STAGED_NODES * NUM_INPUT];  // 31 KB
    __shared__ float lds_b[N_INTERNAL];                // 4 KB
    __shared__ float lds_a[N_INTERNAL];                // 4 KB

    const int tid  = threadIdx.x;
    const int lane = tid & 63;
    const int wid  = tid >> 6;
    const int g    = lane >> 4;   // element slot within wave (0..3)
    const int s    = lane & 15;   // sub-lane within element group
    const int elem = blockIdx.x * ELEMS_PER_BLOCK + wid * ELEMS_PER_WAVE + g;

    // ---- x loads issued BEFORE staging: memory latency hides under stage ----
    const float4* xrow = reinterpret_cast<const float4*>(x + (size_t)elem * NUM_INPUT);
    float4 xv0 = xrow[0 * 16 + s];
    float4 xv1 = xrow[1 * 16 + s];
    float4 xv2 = xrow[2 * 16 + s];
    float4 xv3 = xrow[3 * 16 + s];

    // ---- stage W levels 0..4 (rows 0..30) + all b/alpha ----
    {
        const float4* Wv = reinterpret_cast<const float4*>(W);
        float4* lw4 = reinterpret_cast<float4*>(lds_w);
        #pragma unroll
        for (int i = tid; i < STAGED_NODES * NUM_INPUT / 4; i += THREADS)
            lw4[i] = Wv[i];
        for (int i = tid; i < N_INTERNAL; i += THREADS) {
            lds_b[i] = b[i];
            lds_a[i] = alpha[i];
        }
    }
    __syncthreads();

    int   idx = 0;
    bool  right;
    float zn[MAX_DEPTH];   // -|z_d| per depth; fully unrolled -> registers

    // ---- depths 0..3: W row from LDS, computed directly ----
    #define LDS_STEP(D)                                                    \
    {                                                                      \
        const float4* wrow = reinterpret_cast<const float4*>(              \
            lds_w + idx * NUM_INPUT);                                      \
        float a_i = lds_a[idx];                                            \
        float b_i = lds_b[idx];                                            \
        float4 w0 = wrow[0 * 16 + s];                                      \
        float4 w1 = wrow[1 * 16 + s];                                      \
        float4 w2 = wrow[2 * 16 + s];                                      \
        float4 w3 = wrow[3 * 16 + s];                                      \
        float acc0 = xv0.x * w0.x, acc1 = xv1.x * w1.x;                    \
        float acc2 = xv2.x * w2.x, acc3 = xv3.x * w3.x;                    \
        acc0 = fmaf(xv0.y, w0.y, acc0); acc1 = fmaf(xv1.y, w1.y, acc1);    \
        acc2 = fmaf(xv2.y, w2.y, acc2); acc3 = fmaf(xv3.y, w3.y, acc3);    \
        acc0 = fmaf(xv0.z, w0.z, acc0); acc1 = fmaf(xv1.z, w1.z, acc1);    \
        acc2 = fmaf(xv2.z, w2.z, acc2); acc3 = fmaf(xv3.z, w3.z, acc3);    \
        acc0 = fmaf(xv0.w, w0.w, acc0); acc1 = fmaf(xv1.w, w1.w, acc1);    \
        acc2 = fmaf(xv2.w, w2.w, acc2); acc3 = fmaf(xv3.w, w3.w, acc3);    \
        float acc = (acc0 + acc1) + (acc2 + acc3);                         \
        acc = group16_reduce_add(acc);                                     \
        float z = a_i * (acc + b_i);                                       \
        zn[D] = __int_as_float(__float_as_int(z) | 0x80000000);  /* -|z| */\
        right = (z >= 0.0f);                                               \
        idx = 2 * idx + 1 + (right ? 1 : 0);                               \
    }

    LDS_STEP(0)
    LDS_STEP(1)
    LDS_STEP(2)
    LDS_STEP(3)
    #undef LDS_STEP

    // Speculative pair for the NEXT level, kept in flight across one depth.
    float4 wL0, wL1, wL2, wL3, wR0, wR1, wR2, wR3;

    // ---- depth 4: row from LDS; while computing, issue BOTH level-5
    //      candidate rows (children of idx_4 — contiguous 2 KB) from global ----
    {
        const float4* wrow = reinterpret_cast<const float4*>(lds_w + idx * NUM_INPUT);
        float a_i = lds_a[idx];
        float b_i = lds_b[idx];
        float4 w0 = wrow[0 * 16 + s];
        float4 w1 = wrow[1 * 16 + s];
        float4 w2 = wrow[2 * 16 + s];
        float4 w3 = wrow[3 * 16 + s];
        const float4* pL = reinterpret_cast<const float4*>(W + (size_t)(2 * idx + 1) * NUM_INPUT);
        const float4* pR = reinterpret_cast<const float4*>(W + (size_t)(2 * idx + 2) * NUM_INPUT);
        wL0 = pL[0 * 16 + s]; wL1 = pL[1 * 16 + s];
        wL2 = pL[2 * 16 + s]; wL3 = pL[3 * 16 + s];
        wR0 = pR[0 * 16 + s]; wR1 = pR[1 * 16 + s];
        wR2 = pR[2 * 16 + s]; wR3 = pR[3 * 16 + s];
        float acc0 = xv0.x * w0.x, acc1 = xv1.x * w1.x;
        float acc2 = xv2.x * w2.x, acc3 = xv3.x * w3.x;
        acc0 = fmaf(xv0.y, w0.y, acc0); acc1 = fmaf(xv1.y, w1.y, acc1);
        acc2 = fmaf(xv2.y, w2.y, acc2); acc3 = fmaf(xv3.y, w3.y, acc3);
        acc0 = fmaf(xv0.z, w0.z, acc0); acc1 = fmaf(xv1.z, w1.z, acc1);
        acc2 = fmaf(xv2.z, w2.z, acc2); acc3 = fmaf(xv3.z, w3.z, acc3);
        acc0 = fmaf(xv0.w, w0.w, acc0); acc1 = fmaf(xv1.w, w1.w, acc1);
        acc2 = fmaf(xv2.w, w2.w, acc2); acc3 = fmaf(xv3.w, w3.w, acc3);
        float acc = (acc0 + acc1) + (acc2 + acc3);
        acc = group16_reduce_add(acc);
        float z = a_i * (acc + b_i);
        zn[4] = __int_as_float(__float_as_int(z) | 0x80000000);
        right = (z >= 0.0f);
        idx = 2 * idx + 1 + (right ? 1 : 0);
    }

    // ---- depths 5..8: select pre-loaded row, issue next pair, compute ----
    #define GSTEP(D)                                                       \
    {                                                                      \
        float4 w0 = sel4(right, wR0, wL0);                                 \
        float4 w1 = sel4(right, wR1, wL1);                                 \
        float4 w2 = sel4(right, wR2, wL2);                                 \
        float4 w3 = sel4(right, wR3, wL3);                                 \
        float a_i = lds_a[idx];                                            \
        float b_i = lds_b[idx];                                            \
        const float4* pL = reinterpret_cast<const float4*>(                \
            W + (size_t)(2 * idx + 1) * NUM_INPUT);                        \
        const float4* pR = reinterpret_cast<const float4*>(                \
            W + (size_t)(2 * idx + 2) * NUM_INPUT);                        \
        wL0 = pL[0 * 16 + s]; wL1 = pL[1 * 16 + s];                        \
        wL2 = pL[2 * 16 + s]; wL3 = pL[3 * 16 + s];                        \
        wR0 = pR[0 * 16 + s]; wR1 = pR[1 * 16 + s];                        \
        wR2 = pR[2 * 16 + s]; wR3 = pR[3 * 16 + s];                        \
        float acc0 = xv0.x * w0.x, acc1 = xv1.x * w1.x;                    \
        float acc2 = xv2.x * w2.x, acc3 = xv3.x * w3.x;                    \
        acc0 = fmaf(xv0.y, w0.y, acc0); acc1 = fmaf(xv1.y, w1.y, acc1);    \
        acc2 = fmaf(xv2.y, w2.y, acc2); acc3 = fmaf(xv3.y, w3.y, acc3);    \
        acc0 = fmaf(xv0.z, w0.z, acc0); acc1 = fmaf(xv1.z, w1.z, acc1);    \
        acc2 = fmaf(xv2.z, w2.z, acc2); acc3 = fmaf(xv3.z, w3.z, acc3);    \
        acc0 = fmaf(xv0.w, w0.w, acc0); acc1 = fmaf(xv1.w, w1.w, acc1);    \
        acc2 = fmaf(xv2.w, w2.w, acc2); acc3 = fmaf(xv3.w, w3.w, acc3);    \
        float acc = (acc0 + acc1) + (acc2 + acc3);                         \
        acc = group16_reduce_add(acc);                                     \
        float z = a_i * (acc + b_i);                                       \
        zn[D] = __int_as_float(__float_as_int(z) | 0x80000000);            \
        right = (z >= 0.0f);                                               \
        idx = 2 * idx + 1 + (right ? 1 : 0);                               \
    }

    GSTEP(5)
    GSTEP(6)
    GSTEP(7)
    GSTEP(8)
    #undef GSTEP

    // ---- depth 9: select pre-loaded row; speculatively load BOTH leaf
    //      candidate fragments (contiguous 512 B); compute; select leaf ----
    float4 lvL, lvR;
    {
        float4 w0 = sel4(right, wR0, wL0);
        float4 w1 = sel4(right, wR1, wL1);
        float4 w2 = sel4(right, wR2, wL2);
        float4 w3 = sel4(right, wR3, wL3);
        float a_i = lds_a[idx];
        float b_i = lds_b[idx];
        const int leafL = 2 * idx + 1 - N_INTERNAL;   // leaf if go-left
        lvL = reinterpret_cast<const float4*>(leaves + (size_t)leafL * NUM_OUTPUT)[s];
        lvR = reinterpret_cast<const float4*>(leaves + (size_t)(leafL + 1) * NUM_OUTPUT)[s];
        float acc0 = xv0.x * w0.x, acc1 = xv1.x * w1.x;
        float acc2 = xv2.x * w2.x, acc3 = xv3.x * w3.x;
        acc0 = fmaf(xv0.y, w0.y, acc0); acc1 = fmaf(xv1.y, w1.y, acc1);
        acc2 = fmaf(xv2.y, w2.y, acc2); acc3 = fmaf(xv3.y, w3.y, acc3);
        acc0 = fmaf(xv0.z, w0.z, acc0); acc1 = fmaf(xv1.z, w1.z, acc1);
        acc2 = fmaf(xv2.z, w2.z, acc2); acc3 = fmaf(xv3.z, w3.z, acc3);
        acc0 = fmaf(xv0.w, w0.w, acc0); acc1 = fmaf(xv1.w, w1.w, acc1);
        acc2 = fmaf(xv2.w, w2.w, acc2); acc3 = fmaf(xv3.w, w3.w, acc3);
        float acc = (acc0 + acc1) + (acc2 + acc3);
        acc = group16_reduce_add(acc);
        float z = a_i * (acc + b_i);
        zn[9] = __int_as_float(__float_as_int(z) | 0x80000000);
        right = (z >= 0.0f);
    }

    // ---- deferred sigmoid epilogue (lane-parallel across the 16-lane group):
    // mult = prod_d sigmoid(|z_d|) = 1 / prod_d (1 + exp(-|z_d|)).
    float zsel = -1e30f;
    #pragma unroll
    for (int d = 0; d < MAX_DEPTH; ++d)
        zsel = (s == d) ? zn[d] : zsel;
    float f = 1.0f + __expf(zsel);          // one trans op per element
    float p = group16_reduce_mul(f);        // prod over the 16-lane row
    float mult = 1.0f / p;

    // ---- out[elem] = mult * selected leaf fragment ----
    const float4 lv = sel4(right, lvR, lvL);
    float4 o;
    o.x = mult * lv.x;
    o.y = mult * lv.y;
    o.z = mult * lv.z;
    o.w = mult * lv.w;
    reinterpret_cast<float4*>(out + (size_t)elem * NUM_OUTPUT)[s] = o;
}

extern "C" void kernel_launch(void* const* d_in, const int* in_sizes, int n_in,
                              void* d_out, int out_size, void* d_ws, size_t ws_size,
                              hipStream_t stream) {
    const float* x      = (const float*)d_in[0];
    const float* W      = (const float*)d_in[1];
    const float* b      = (const float*)d_in[2];
    const float* alpha  = (const float*)d_in[3];
    const float* leaves = (const float*)d_in[4];
    float* out = (float*)d_out;

    const int batch  = in_sizes[0] / NUM_INPUT;           // 131072
    const int blocks = batch / ELEMS_PER_BLOCK;           // 4096

    ogtree_kernel<<<blocks, THREADS, 0, stream>>>(x, W, b, alpha, leaves, out);
}